// Round 10
// baseline (58.095 us; speedup 1.0000x reference)
//
#include <hip/hip_runtime.h>
#include <math.h>

// M is (64, 512, 28, 28) fp32.
#define BB 64
#define CC 512
#define HWP 784                 // px per map
#define NF4 196                 // float4 groups per map
#define NCHUNK 16               // channel chunks (32 ch each)
#define NPIX4 12544             // (64*784)/4 float4 pixel-groups
#define PLANE4 200704           // NCHUNK * NPIX4 float4 per plane
#define DIS_SLOTS 8192          // 64 b * 16 chunks * 8 waves
#define DIV_SLOTS 196
#define NEG_FILL -999999.0f
#define NTOT 25690112.0         // 64*512*28*28

static __device__ __forceinline__ unsigned sortable(float v) {
  unsigned b = __float_as_uint(v);
  return (b & 0x80000000u) ? ~b : (b | 0x80000000u);
}
static __device__ __forceinline__ void top2(float v, float& v1, float& v2) {
  float lo = fminf(v, v1);
  v1 = fmaxf(v1, v);
  v2 = fmaxf(v2, lo);
}
static __device__ __forceinline__ void mergev(float& v1, float& v2, float b1, float b2) {
  float lo = fminf(v1, b1);
  v1 = fmaxf(v1, b1);
  v2 = fmaxf(lo, fmaxf(v2, b2));
}
static __device__ __forceinline__ void mergev4(float4& v1, float4& v2, float4 b1, float4 b2) {
  mergev(v1.x, v2.x, b1.x, b2.x);
  mergev(v1.y, v2.y, b1.y, b2.y);
  mergev(v1.z, v2.z, b1.z, b2.z);
  mergev(v1.w, v2.w, b1.w, b2.w);
}

// ---------------- fused single-pass kernel ----------------
// block = (chunk, b): 32 ch x 784 px; 8 waves x 4 ch/wave (512 threads).
// Per position-pass (64 float4-groups): consume 4 channels -> per-pass
// cross-wave LDS fold (only 3 KB LDS/wave vs 9.4 KB before) -> ws write.
// Goal: VGPR <= 64 live set + 24.6 KB LDS/block -> 4 blocks/CU = 32 waves/CU
// (2x round-9 occupancy; the measured 2.5-3 TB/s warm BW scales with waves).
__global__ __launch_bounds__(512)
void fused_kernel(const float* __restrict__ M,
    double* __restrict__ slots, float4* __restrict__ wsV1, float4* __restrict__ wsV2,
    float4* __restrict__ wsS, unsigned* __restrict__ counter) {
  const int t     = threadIdx.x;
  const int lane  = t & 63;
  const int w     = t >> 6;               // 0..7
  const int chunk = blockIdx.x;           // 0..15
  const int b     = blockIdx.y;           // 0..63
  if (chunk == 0 && b == 0 && t == 0) *counter = 0u;   // ticket reset

  const float4* base4 =
      (const float4*)(M + ((size_t)b * CC + chunk * 32 + w * 4) * HWP);

  float s0[4], sy[4], sx[4], bv[4];
  int bi[4];
  #pragma unroll
  for (int c = 0; c < 4; ++c) { s0[c]=0.f; sy[c]=0.f; sx[c]=0.f; bv[c]=-INFINITY; bi[c]=0; }
  float srr = 0.f;                        // sum M*(y^2+x^2), lane slice

  __shared__ float4 sv1[8][64], sv2[8][64], sS[8][64];   // 24576 B

  #pragma unroll
  for (int k = 0; k < 4; ++k) {
    const bool tail = (k == 3);
    const int  f    = tail ? (192 + (lane & 3)) : (lane + 64 * k);
    const bool fake = tail && (lane >= 4);

    const int y = f / 7;                  // 7 float4-groups per row
    const float fy  = (float)y;
    const float fx0 = (float)((f - y * 7) * 4);
    const float fx1 = fx0 + 1.f, fx2 = fx0 + 2.f, fx3 = fx0 + 3.f;
    const float fyy = fy * fy;
    const float rr0 = fyy + fx0*fx0, rr1 = fyy + fx1*fx1;
    const float rr2 = fyy + fx2*fx2, rr3 = fyy + fx3*fx3;
    const int pxb = f * 4;

    float4 d[4];
    #pragma unroll
    for (int c = 0; c < 4; ++c) d[c] = base4[c * NF4 + f];

    const float NI = -INFINITY;
    float4 v1 = make_float4(NI, NI, NI, NI);
    float4 v2 = v1;
    float4 S  = make_float4(0.f, 0.f, 0.f, 0.f);

    #pragma unroll
    for (int c = 0; c < 4; ++c) {
      float a0 = d[c].x, a1 = d[c].y, a2 = d[c].z, a3 = d[c].w;
      if (fake) { a0 = a1 = a2 = a3 = 0.f; }
      const float q0 = fake ? NI : a0, q1 = fake ? NI : a1;
      const float q2 = fake ? NI : a2, q3 = fake ? NI : a3;
      const float sum4 = (a0 + a1) + (a2 + a3);
      s0[c] += sum4;
      sy[c] = fmaf(sum4, fy, sy[c]);
      sx[c] = fmaf(a0, fx0, sx[c]); sx[c] = fmaf(a1, fx1, sx[c]);
      sx[c] = fmaf(a2, fx2, sx[c]); sx[c] = fmaf(a3, fx3, sx[c]);
      srr = fmaf(a0, rr0, srr); srr = fmaf(a1, rr1, srr);
      srr = fmaf(a2, rr2, srr); srr = fmaf(a3, rr3, srr);
      if (q0 > bv[c]) { bv[c] = q0; bi[c] = pxb;     }
      if (q1 > bv[c]) { bv[c] = q1; bi[c] = pxb + 1; }
      if (q2 > bv[c]) { bv[c] = q2; bi[c] = pxb + 2; }
      if (q3 > bv[c]) { bv[c] = q3; bi[c] = pxb + 3; }
      top2(q0, v1.x, v2.x); S.x += a0;
      top2(q1, v1.y, v2.y); S.y += a1;
      top2(q2, v1.z, v2.z); S.z += a2;
      top2(q3, v1.w, v2.w); S.w += a3;
    }
    if (!fake) { sv1[w][lane] = v1; sv2[w][lane] = v2; sS[w][lane] = S; }
    __syncthreads();

    // per-pass cross-wave fold: wave 0 merges (v1,v2), wave 1 sums S
    const int glim = tail ? 4 : 64;
    if (t < glim) {
      float4 mv1 = sv1[0][t], mv2 = sv2[0][t];
      #pragma unroll
      for (int ww = 1; ww < 8; ++ww) mergev4(mv1, mv2, sv1[ww][t], sv2[ww][t]);
      const int idx = chunk * NPIX4 + b * NF4 + k * 64 + t;
      wsV1[idx] = mv1; wsV2[idx] = mv2;
    } else if (t >= 64 && t < 64 + glim) {
      const int g = t - 64;
      float4 mS = sS[0][g];
      #pragma unroll
      for (int ww = 1; ww < 8; ++ww) {
        float4 bS = sS[ww][g];
        mS.x += bS.x; mS.y += bS.y; mS.z += bS.z; mS.w += bS.w;
      }
      wsS[chunk * NPIX4 + b * NF4 + k * 64 + g] = mS;
    }
    __syncthreads();
  }

  // ---- dis epilogue: per-channel argmax butterfly, lane-local contribution ----
  double dis_acc = (double)srr;
  #pragma unroll
  for (int c = 0; c < 4; ++c) {
    unsigned long long key =
        ((unsigned long long)sortable(bv[c]) << 32) | (unsigned)(~bi[c]);
    #pragma unroll
    for (int off = 1; off < 64; off <<= 1) {
      unsigned long long o = __shfl_xor(key, off);
      key = (key > o) ? key : o;            // max val; tie -> min px
    }
    const int px = (int)(~((unsigned)key));
    const int iy = px / 28;
    const int ix = px - iy * 28;
    dis_acc += (double)s0[c] * (double)(iy * iy + ix * ix)
             - 2.0 * ((double)sy[c] * (double)iy + (double)sx[c] * (double)ix);
  }
  #pragma unroll
  for (int off = 32; off >= 1; off >>= 1)
    dis_acc += __shfl_down(dis_acc, off);
  if (lane == 0)
    slots[((b * NCHUNK + chunk) << 3) | w] = dis_acc;   // unique slot, plain store
}

// ---------------- merge chunk partials -> div; last block finalizes ----------------
__global__ __launch_bounds__(256) void div_merge_kernel(const float4* __restrict__ wsV1,
    const float4* __restrict__ wsV2, const float4* __restrict__ wsS,
    double* __restrict__ slots, unsigned* __restrict__ counter,
    float* __restrict__ out) {
  const int t = threadIdx.x, lane = t & 63, w = t >> 6;
  const int g = blockIdx.x * 64 + lane;

  float4 a1[4], a2[4], aS[4];
  #pragma unroll
  for (int c = 0; c < 4; ++c) {
    const int idx = (w * 4 + c) * NPIX4 + g;
    a1[c] = wsV1[idx]; a2[c] = wsV2[idx]; aS[c] = wsS[idx];
  }
  float4 v1 = a1[0], v2 = a2[0], S = aS[0];
  #pragma unroll
  for (int c = 1; c < 4; ++c) {
    mergev4(v1, v2, a1[c], a2[c]);
    S.x += aS[c].x; S.y += aS[c].y; S.z += aS[c].z; S.w += aS[c].w;
  }
  __shared__ float4 sm[4][3][64];
  sm[w][0][lane] = v1; sm[w][1][lane] = v2; sm[w][2][lane] = S;
  __syncthreads();

  if (t < 64) {
    v1 = sm[0][0][t]; v2 = sm[0][1][t]; S = sm[0][2][t];
    #pragma unroll
    for (int ww = 1; ww < 4; ++ww) {
      mergev4(v1, v2, sm[ww][0][t], sm[ww][1][t]);
      float4 bS = sm[ww][2][t];
      S.x += bS.x; S.y += bS.y; S.z += bS.z; S.w += bS.w;
    }
    // sum_c loo_c*M_c = clamp(v1)*(S - v1) + clamp(v2)*v1  (per pixel)
    double contrib =
        (double)fmaxf(v1.x, NEG_FILL) * ((double)S.x - (double)v1.x) + (double)fmaxf(v2.x, NEG_FILL) * (double)v1.x
      + (double)fmaxf(v1.y, NEG_FILL) * ((double)S.y - (double)v1.y) + (double)fmaxf(v2.y, NEG_FILL) * (double)v1.y
      + (double)fmaxf(v1.z, NEG_FILL) * ((double)S.z - (double)v1.z) + (double)fmaxf(v2.z, NEG_FILL) * (double)v1.z
      + (double)fmaxf(v1.w, NEG_FILL) * ((double)S.w - (double)v1.w) + (double)fmaxf(v2.w, NEG_FILL) * (double)v1.w;
    #pragma unroll
    for (int off = 32; off >= 1; off >>= 1)
      contrib += __shfl_down(contrib, off);
    if (t == 0)
      slots[DIS_SLOTS + blockIdx.x] = contrib;
  }

  // ---- last-block finalize (ticket) ----
  __shared__ unsigned ticket_s;
  __threadfence();
  __syncthreads();
  if (t == 0) ticket_s = atomicAdd(counter, 1u);
  __syncthreads();
  if (ticket_s == DIV_SLOTS - 1) {
    __threadfence();
    double dis = 0.0;
    #pragma unroll
    for (int i = 0; i < 32; ++i) dis += slots[t + (i << 8)];
    double dv = (t < DIV_SLOTS) ? slots[DIS_SLOTS + t] : 0.0;
    #pragma unroll
    for (int off = 32; off >= 1; off >>= 1) {
      dis += __shfl_down(dis, off);
      dv  += __shfl_down(dv,  off);
    }
    __shared__ double pd[4], pv[4];
    if (lane == 0) { pd[w] = dis; pv[w] = dv; }
    __syncthreads();
    if (t == 0) {
      out[0] = (float)((pd[0] + pd[1] + pd[2] + pd[3]) / NTOT);
      out[1] = (float)((pv[0] + pv[1] + pv[2] + pv[3]) / NTOT);
    }
  }
}

extern "C" void kernel_launch(void* const* d_in, const int* in_sizes, int n_in,
                              void* d_out, int out_size, void* d_ws, size_t ws_size,
                              hipStream_t stream) {
  const float* M = (const float*)d_in[0];
  double*   slots   = (double*)d_ws;                        // 8192+196 doubles
  unsigned* counter = (unsigned*)((char*)d_ws + 67584);
  float4*   planes  = (float4*)((char*)d_ws + 69632);       // 3 planes of PLANE4 float4
  float4* wsV1 = planes;
  float4* wsV2 = planes + PLANE4;
  float4* wsS  = planes + 2 * (size_t)PLANE4;
  fused_kernel<<<dim3(NCHUNK, BB), 512, 0, stream>>>(M, slots, wsV1, wsV2, wsS, counter);
  div_merge_kernel<<<DIV_SLOTS, 256, 0, stream>>>(wsV1, wsV2, wsS, slots, counter,
                                                  (float*)d_out);
}

// Round 11
// 45.793 us; speedup vs baseline: 1.2686x; 1.2686x over previous
//
#include <hip/hip_runtime.h>
#include <math.h>

// M is (64, 512, 28, 28) fp32.
#define BB 64
#define CC 512
#define HWP 784                 // px per map
#define NF4 196                 // float4 groups per map
#define NCHUNK 32               // channel chunks (16 ch each)
#define NPIX4 12544             // (64*784)/4 float4 pixel-groups
#define PLANE4 401408           // NCHUNK * NPIX4 float4 per plane (6.4 MB)
#define DIS_SLOTS 8192          // 64 b * 32 chunks * 4 waves
#define DIV_SLOTS 196
#define NEG_FILL -999999.0f
#define NTOT 25690112.0         // 64*512*28*28

static __device__ __forceinline__ unsigned sortable(float v) {
  unsigned b = __float_as_uint(v);
  return (b & 0x80000000u) ? ~b : (b | 0x80000000u);
}
static __device__ __forceinline__ void top2(float v, float& v1, float& v2) {
  float lo = fminf(v, v1);
  v1 = fmaxf(v1, v);
  v2 = fmaxf(v2, lo);
}
static __device__ __forceinline__ void mergev(float& v1, float& v2, float b1, float b2) {
  float lo = fminf(v1, b1);
  v1 = fmaxf(v1, b1);
  v2 = fmaxf(lo, fmaxf(v2, b2));
}
static __device__ __forceinline__ void mergev4(float4& v1, float4& v2, float4 b1, float4 b2) {
  mergev(v1.x, v2.x, b1.x, b2.x);
  mergev(v1.y, v2.y, b1.y, b2.y);
  mergev(v1.z, v2.z, b1.z, b2.z);
  mergev(v1.w, v2.w, b1.w, b2.w);
}

// ---------------- fused single-pass kernel ----------------
// block = (chunk, b): 16 ch x 784 px; 4 waves x 4 ch/wave (256 threads).
// 4 UNIFORM passes of 49 float4-groups (lanes 49..63 fake) + per-pass
// cross-wave LDS fold. Register target <= 64 VGPR (m69 cliff: <=64 -> 8
// waves/SIMD) and LDS 9.4 KB -> 8 blocks/CU = 32 waves/CU, 2x all prior
// rounds (every 16-wave variant plateaued at warm ~2.5-3 TB/s, VALUBusy
// ~17-21% = latency-bound on concurrency).
__global__ __launch_bounds__(256)
void fused_kernel(const float* __restrict__ M,
    double* __restrict__ slots, float4* __restrict__ wsV1, float4* __restrict__ wsV2,
    float4* __restrict__ wsS) {
  const int t     = threadIdx.x;
  const int lane  = t & 63;
  const int w     = t >> 6;               // 0..3
  const int chunk = blockIdx.x;           // 0..31
  const int b     = blockIdx.y;           // 0..63

  const float4* base4 =
      (const float4*)(M + ((size_t)b * CC + chunk * 16 + w * 4) * HWP);

  float s0[4], sy[4], sx[4], bv[4];
  int bi[4];
  #pragma unroll
  for (int c = 0; c < 4; ++c) { s0[c]=0.f; sy[c]=0.f; sx[c]=0.f; bv[c]=-INFINITY; bi[c]=0; }
  float srr = 0.f;                        // sum M*(y^2+x^2), lane slice

  __shared__ float4 sv1[4][49], sv2[4][49], sS[4][49];   // 9408 B

  const bool fake = (lane >= 49);

  #pragma unroll
  for (int k = 0; k < 4; ++k) {
    const int fr = 49 * k + lane;         // real group id for active lanes
    const int f  = fr > 195 ? 195 : fr;   // clamped load addr for fake lanes

    const int y = f / 7;                  // 7 float4-groups per row
    const float fy  = (float)y;
    const float fx0 = (float)((f - y * 7) * 4);
    const float fx1 = fx0 + 1.f, fx2 = fx0 + 2.f, fx3 = fx0 + 3.f;
    const float fyy = fy * fy;
    const int pxb = f * 4;

    float4 d[4];
    #pragma unroll
    for (int c = 0; c < 4; ++c) d[c] = base4[c * NF4 + f];

    const float NI = -INFINITY;
    float4 v1 = make_float4(NI, NI, NI, NI);
    float4 v2 = v1;
    float4 S  = make_float4(0.f, 0.f, 0.f, 0.f);

    #pragma unroll
    for (int c = 0; c < 4; ++c) {
      float a0 = d[c].x, a1 = d[c].y, a2 = d[c].z, a3 = d[c].w;
      if (fake) { a0 = a1 = a2 = a3 = NI; }
      // sums use zeroed copies; compares use NI copies — derive both from one
      const float z0 = fake ? 0.f : a0, z1 = fake ? 0.f : a1;
      const float z2 = fake ? 0.f : a2, z3 = fake ? 0.f : a3;
      const float sum4 = (z0 + z1) + (z2 + z3);
      s0[c] += sum4;
      sy[c] = fmaf(sum4, fy, sy[c]);
      srr   = fmaf(sum4, fyy, srr);              // y^2 part via shared y
      float t0 = z0 * fx0; sx[c] += t0; srr = fmaf(t0, fx0, srr);
      float t1 = z1 * fx1; sx[c] += t1; srr = fmaf(t1, fx1, srr);
      float t2 = z2 * fx2; sx[c] += t2; srr = fmaf(t2, fx2, srr);
      float t3 = z3 * fx3; sx[c] += t3; srr = fmaf(t3, fx3, srr);
      if (a0 > bv[c]) { bv[c] = a0; bi[c] = pxb;     }
      if (a1 > bv[c]) { bv[c] = a1; bi[c] = pxb + 1; }
      if (a2 > bv[c]) { bv[c] = a2; bi[c] = pxb + 2; }
      if (a3 > bv[c]) { bv[c] = a3; bi[c] = pxb + 3; }
      top2(a0, v1.x, v2.x); S.x += z0;
      top2(a1, v1.y, v2.y); S.y += z1;
      top2(a2, v1.z, v2.z); S.z += z2;
      top2(a3, v1.w, v2.w); S.w += z3;
    }
    if (!fake) { sv1[w][lane] = v1; sv2[w][lane] = v2; sS[w][lane] = S; }
    __syncthreads();

    // per-pass cross-wave fold over the block's 16 channels
    if (t < 49) {
      float4 mv1 = sv1[0][t], mv2 = sv2[0][t];
      #pragma unroll
      for (int ww = 1; ww < 4; ++ww) mergev4(mv1, mv2, sv1[ww][t], sv2[ww][t]);
      const int idx = chunk * NPIX4 + b * NF4 + 49 * k + t;
      wsV1[idx] = mv1; wsV2[idx] = mv2;
    } else if (t >= 64 && t < 113) {
      const int g = t - 64;
      float4 mS = sS[0][g];
      #pragma unroll
      for (int ww = 1; ww < 4; ++ww) {
        float4 bS = sS[ww][g];
        mS.x += bS.x; mS.y += bS.y; mS.z += bS.z; mS.w += bS.w;
      }
      wsS[chunk * NPIX4 + b * NF4 + 49 * k + g] = mS;
    }
    __syncthreads();
  }

  // ---- dis epilogue: per-channel argmax butterfly, lane-local contribution ----
  double dis_acc = (double)srr;
  #pragma unroll
  for (int c = 0; c < 4; ++c) {
    unsigned long long key =
        ((unsigned long long)sortable(bv[c]) << 32) | (unsigned)(~bi[c]);
    #pragma unroll
    for (int off = 1; off < 64; off <<= 1) {
      unsigned long long o = __shfl_xor(key, off);
      key = (key > o) ? key : o;            // max val; tie -> min px
    }
    const int px = (int)(~((unsigned)key));
    const int iy = px / 28;
    const int ix = px - iy * 28;
    dis_acc += (double)s0[c] * (double)(iy * iy + ix * ix)
             - 2.0 * ((double)sy[c] * (double)iy + (double)sx[c] * (double)ix);
  }
  #pragma unroll
  for (int off = 32; off >= 1; off >>= 1)
    dis_acc += __shfl_down(dis_acc, off);
  if (lane == 0)
    slots[((b * NCHUNK + chunk) << 2) | w] = dis_acc;   // unique slot, plain store
}

// ---------------- merge chunk partials -> div contribs ----------------
// 196 blocks x 256: wave w folds chunks 8w..8w+7 for its 64 pixel-groups.
__global__ __launch_bounds__(256) void div_merge_kernel(const float4* __restrict__ wsV1,
    const float4* __restrict__ wsV2, const float4* __restrict__ wsS,
    double* __restrict__ slots) {
  const int t = threadIdx.x, lane = t & 63, w = t >> 6;
  const int g = blockIdx.x * 64 + lane;

  float4 v1, v2, S;
  {
    const int idx0 = (w * 8) * NPIX4 + g;
    v1 = wsV1[idx0]; v2 = wsV2[idx0]; S = wsS[idx0];
  }
  #pragma unroll
  for (int c = 1; c < 8; ++c) {
    const int idx = (w * 8 + c) * NPIX4 + g;
    float4 b1 = wsV1[idx], b2 = wsV2[idx], bS = wsS[idx];
    mergev4(v1, v2, b1, b2);
    S.x += bS.x; S.y += bS.y; S.z += bS.z; S.w += bS.w;
  }
  __shared__ float4 sm[4][3][64];
  sm[w][0][lane] = v1; sm[w][1][lane] = v2; sm[w][2][lane] = S;
  __syncthreads();

  if (t < 64) {
    v1 = sm[0][0][t]; v2 = sm[0][1][t]; S = sm[0][2][t];
    #pragma unroll
    for (int ww = 1; ww < 4; ++ww) {
      mergev4(v1, v2, sm[ww][0][t], sm[ww][1][t]);
      float4 bS = sm[ww][2][t];
      S.x += bS.x; S.y += bS.y; S.z += bS.z; S.w += bS.w;
    }
    // sum_c loo_c*M_c = clamp(v1)*(S - v1) + clamp(v2)*v1  (per pixel)
    double contrib =
        (double)fmaxf(v1.x, NEG_FILL) * ((double)S.x - (double)v1.x) + (double)fmaxf(v2.x, NEG_FILL) * (double)v1.x
      + (double)fmaxf(v1.y, NEG_FILL) * ((double)S.y - (double)v1.y) + (double)fmaxf(v2.y, NEG_FILL) * (double)v1.y
      + (double)fmaxf(v1.z, NEG_FILL) * ((double)S.z - (double)v1.z) + (double)fmaxf(v2.z, NEG_FILL) * (double)v1.z
      + (double)fmaxf(v1.w, NEG_FILL) * ((double)S.w - (double)v1.w) + (double)fmaxf(v2.w, NEG_FILL) * (double)v1.w;
    #pragma unroll
    for (int off = 32; off >= 1; off >>= 1)
      contrib += __shfl_down(contrib, off);
    if (t == 0)
      slots[DIS_SLOTS + blockIdx.x] = contrib;          // unique slot, plain store
  }
}

// ---------------- finalize: sum 8192 dis + 196 div partials ----------------
__global__ __launch_bounds__(256) void finalize_kernel(const double* __restrict__ slots,
                                                       float* __restrict__ out) {
  const int t = threadIdx.x, lane = t & 63, wv = t >> 6;
  double dis = 0.0;
  #pragma unroll
  for (int i = 0; i < 32; ++i) dis += slots[t + (i << 8)];
  double dv = (t < DIV_SLOTS) ? slots[DIS_SLOTS + t] : 0.0;
  #pragma unroll
  for (int off = 32; off >= 1; off >>= 1) {
    dis += __shfl_down(dis, off);
    dv  += __shfl_down(dv,  off);
  }
  __shared__ double pd[4], pv[4];
  if (lane == 0) { pd[wv] = dis; pv[wv] = dv; }
  __syncthreads();
  if (t == 0) {
    out[0] = (float)((pd[0] + pd[1] + pd[2] + pd[3]) / NTOT);
    out[1] = (float)((pv[0] + pv[1] + pv[2] + pv[3]) / NTOT);
  }
}

extern "C" void kernel_launch(void* const* d_in, const int* in_sizes, int n_in,
                              void* d_out, int out_size, void* d_ws, size_t ws_size,
                              hipStream_t stream) {
  const float* M = (const float*)d_in[0];
  double* slots  = (double*)d_ws;                        // 8192+196 doubles = 67.1 KB
  float4* planes = (float4*)((char*)d_ws + 69632);       // 3 planes of PLANE4 float4
  float4* wsV1 = planes;
  float4* wsV2 = planes + PLANE4;
  float4* wsS  = planes + 2 * (size_t)PLANE4;
  fused_kernel<<<dim3(NCHUNK, BB), 256, 0, stream>>>(M, slots, wsV1, wsV2, wsS);
  div_merge_kernel<<<DIV_SLOTS, 256, 0, stream>>>(wsV1, wsV2, wsS, slots);
  finalize_kernel<<<1, 256, 0, stream>>>(slots, (float*)d_out);
}